// Round 12
// baseline (124.154 us; speedup 1.0000x reference)
//
#include <hip/hip_runtime.h>

#define N 8192
#define NCLS 81
#define PAD 300
#define NPANEL 16
#define PANW 512

typedef unsigned long long u64;

#define WAITVM0() asm volatile("s_waitcnt vmcnt(0)" ::: "memory")

__device__ __forceinline__ void gload_lds16(const void* g, void* l) {
  __builtin_amdgcn_global_load_lds(
      (const __attribute__((address_space(1))) unsigned int*)g,
      (__attribute__((address_space(3))) unsigned int*)l, 16, 0, 0);
}

// ---------------- K1: decode, 8 lanes per row (coalesced 32B segments) ----------------
__global__ __launch_bounds__(256) void decode_kernel(
    const float* __restrict__ meta, const float* __restrict__ deltas,
    const float* __restrict__ proposals, const float* __restrict__ scores,
    float4* __restrict__ sel, u64* __restrict__ keys, int* __restrict__ rank) {
  int tid = threadIdx.x;
  int row = blockIdx.x * 32 + (tid >> 3);
  int sub = tid & 7;
  const float* srow = scores + (size_t)row * NCLS;
  float bs = -1e30f, ms = -1e30f;
  int best = 0;
  for (int c = sub; c < NCLS; c += 8) {
    float v = srow[c];
    if (v > bs) { bs = v; best = c; }  // ascending c: local first-max
    if (c > 0) ms = fmaxf(ms, v);
  }
  // 8-lane reduce: (max val, min class idx on ties) == global first-max (jnp.argmax)
#pragma unroll
  for (int d = 1; d < 8; d <<= 1) {
    float ob = __shfl_xor(bs, d);
    int oi = __shfl_xor(best, d);
    float om = __shfl_xor(ms, d);
    if (ob > bs || (ob == bs && oi < best)) { bs = ob; best = oi; }
    ms = fmaxf(ms, om);
  }
  if (sub == 0) {
    float W = meta[1], sc = meta[2], H = meta[0];
    const float* p = proposals + row * 4;
    float x1 = p[0] / sc, y1 = p[1] / sc, x2 = p[2] / sc, y2 = p[3] / sc;
    float w = x2 - x1 + 1.0f, h = y2 - y1 + 1.0f;
    float cx = x1 + 0.5f * w, cy = y1 + 0.5f * h;
    float4 d4 = *(const float4*)(deltas + (size_t)row * (4 * NCLS) + best * 4);  // 16B aligned
    float pcx = d4.x * w + cx, pcy = d4.y * h + cy;
    float pw = expf(d4.z) * w, ph = expf(d4.w) * h;
    float lx = W - 1.0f, ly = H - 1.0f;
    float ox1 = fminf(fmaxf(pcx - 0.5f * pw, 0.0f), lx);
    float oy1 = fminf(fmaxf(pcy - 0.5f * ph, 0.0f), ly);
    float ox2 = fminf(fmaxf(pcx + 0.5f * pw, 0.0f), lx);
    float oy2 = fminf(fmaxf(pcy + 0.5f * ph, 0.0f), ly);
    sel[row] = make_float4(ox1, oy1, ox2, oy2);
    keys[row] = ((u64)(~__float_as_uint(ms)) << 32) | (unsigned)row;
    rank[row] = 0;
  }
}

// ---------------- K2a: brute-force rank, LDS-tiled (stable sort of unique keys) ------
__global__ __launch_bounds__(256) void rank_kernel(
    const u64* __restrict__ keys, int* __restrict__ rank) {
  __shared__ u64 kt[256];
  int tid = threadIdx.x;
  int i = blockIdx.x * 256 + tid;
  kt[tid] = keys[blockIdx.y * 256 + tid];
  u64 ki = keys[i];
  __syncthreads();
  int c = 0;
#pragma unroll 8
  for (int t = 0; t < 256; ++t) c += (kt[t] < ki);
  atomicAdd(&rank[i], c);
}

// ---------------- K2b: scatter into sorted order ----------------
__global__ __launch_bounds__(256) void scatter_kernel(
    const int* __restrict__ rank, const float4* __restrict__ sel,
    int* __restrict__ sortedIdx, float4* __restrict__ sortedBoxes) {
  int i = blockIdx.x * 256 + threadIdx.x;
  int r = rank[i];
  sortedIdx[r] = i;
  sortedBoxes[r] = sel[i];
}

// ---------------- K3: suppression bitmask — occupancy-first tiling (R10 proven) ------
__global__ __launch_bounds__(256) void mask_kernel(
    const float4* __restrict__ boxes, u64* __restrict__ mask) {
  int q = blockIdx.x;   // col-group of 128
  int ry = blockIdx.y;  // row-group of 256
  int jbase = q * 128, rbase = ry * 256;
  if (jbase + 128 <= rbase) return;  // strictly lower-tri block
  __shared__ float4 cbox[128];
  __shared__ float carea[128];
  int tid = threadIdx.x;
  if (tid < 128) {
    float4 b = boxes[jbase + tid];
    cbox[tid] = b;
    carea[tid] = fmaxf(b.z - b.x, 0.0f) * fmaxf(b.w - b.y, 0.0f);
  }
  __syncthreads();
  int r = rbase + tid;
  int rel = r - jbase;      // bits valid only for cc > rel
  if (rel >= 128) return;   // both words strictly lower-tri: stay poison (never read)
  float4 bi = boxes[r];
  float areaA = fmaxf(bi.z - bi.x, 0.0f) * fmaxf(bi.w - bi.y, 0.0f);
  u64 out2[2];
#pragma unroll
  for (int w = 0; w < 2; ++w) {
    unsigned lo = 0, hi = 0;
#pragma unroll 16
    for (int c = 0; c < 64; ++c) {
      int cc = (w << 6) + c;
      float4 bj = cbox[cc];
      float lxv = fmaxf(bi.x, bj.x), lyv = fmaxf(bi.y, bj.y);
      float rxv = fminf(bi.z, bj.z), ryv = fminf(bi.w, bj.w);
      float iw = fmaxf(rxv - lxv, 0.0f), ih = fmaxf(ryv - lyv, 0.0f);
      float inter = iw * ih;
      float u = areaA + carea[cc] - inter + 1e-8f;  // exact ref assoc order
      float sA = inter * 33554432.0f;  // * 2^25, exact
      float sB = u * 16777216.0f;      // * 2^24, exact
      unsigned sup = (((sA - sB) - u) > 0.0f) ? 1u : 0u;
      if (c < 32) lo |= sup << c; else hi |= sup << (c - 32);
    }
    u64 bits = ((u64)hi << 32) | lo;
    int relw = rel - (w << 6);            // need c > relw within this word
    if (relw >= 63) bits = 0ull;
    else if (relw >= 0) bits &= ~((1ull << (relw + 1)) - 1ull);
    out2[w] = bits;
  }
  *(ulonglong2*)(mask + (size_t)r * 128 + q * 2) = make_ulonglong2(out2[0], out2[1]);
}

// ---------------- K4: greedy scan, 2 waves, panel-boundary-only handshake --------
// Wave0 (scanner): pure LDS+VALU. Per keep: 4 ds_read_b64 (broadcast mA/mB +
// per-lane-group sA/sB into distributed panel remv), spec-2. Word advance =
// 1 shfl. Publishes keeps via LDS writes only. NO VM ops, NO mid-panel waits
// (R7's failure mode). Wave1 (folder): all global traffic — slab prefetch +
// concurrent full-row fold into its own registers; at each panel boundary
// finishes stragglers and hands wave0 the next panel's 8 remv words (rvbuf).
// Monotonic prep/done counters; 0x7F = finished sentinel. Poison invariant:
// folded rows' lower-tri words only contaminate col-blocks < 8(p+1), and rvbuf
// extraction reads words >= 8(p+1) — never poison (same argument as R6).
__global__ __launch_bounds__(128) void nms_scan_kernel(
    const u64* __restrict__ mask, int* __restrict__ kept, int* __restrict__ num_kept) {
  __shared__ u64 slab[2][PANW * 8];  // 2 x 32 KiB diagonal slabs
  __shared__ u64 rvbuf[8];           // next panel's remv words (wave1 -> wave0)
  __shared__ int keptGi[PAD];
  __shared__ int ctl[4];             // [0]=cnt published, [1]=done panel, [2]=prep
  volatile int* vctl = ctl;
  volatile int* vkept = keptGi;
  volatile u64* vrv = rvbuf;
  const char* mb = (const char*)mask;
  int tid = threadIdx.x;
  int lane = tid & 63;

  if (tid == 0) { ctl[0] = 0; ctl[1] = 0; ctl[2] = 0; }
  __syncthreads();

  if (tid >= 64) {
    // ================= wave 1: folder / prefetcher =================
    u64 own0 = 0ull, own1 = 0ull;  // lane owns global remv words 2l, 2l+1
    // slab panel 0
#pragma unroll
    for (int it = 0; it < 32; ++it)
      gload_lds16(mb + (size_t)(it * 16 + (lane >> 2)) * 1024 + (lane & 3) * 16,
                  &slab[0][0] + it * 128);
    WAITVM0();
    if (lane < 8) vrv[lane] = 0ull;
    __threadfence_block();
    if (lane == 0) vctl[2] = 1;  // panel 0 prepared

    int folded = 0;
    for (int p = 0; p < NPANEL; ++p) {
      if (p < NPANEL - 1) {  // issue slab p+1 (buffer held p-1; wave0 is done with it)
        int q = p + 1;
        const char* sb = mb + (size_t)(q * PANW) * 1024 + (size_t)q * 64;
        u64* dst = &slab[q & 1][0];
#pragma unroll
        for (int it = 0; it < 32; ++it)
          gload_lds16(sb + (size_t)(it * 16 + (lane >> 2)) * 1024 + (lane & 3) * 16,
                      dst + it * 128);
      }
      bool finished = false;
      while (true) {
        int done = vctl[1];  // read done BEFORE cnt (LDS in-order): done==p+1 => cv final
        int cv = vctl[0];
        while (folded < cv) {  // fold new keeps, 8-batched ILP (global->VGPR)
          int m = cv - folded;
          if (m > 8) m = 8;
          int g0 = 0, g1 = 0, g2 = 0, g3 = 0, g4 = 0, g5 = 0, g6 = 0, g7 = 0;
          if (0 < m) g0 = vkept[folded + 0];
          if (1 < m) g1 = vkept[folded + 1];
          if (2 < m) g2 = vkept[folded + 2];
          if (3 < m) g3 = vkept[folded + 3];
          if (4 < m) g4 = vkept[folded + 4];
          if (5 < m) g5 = vkept[folded + 5];
          if (6 < m) g6 = vkept[folded + 6];
          if (7 < m) g7 = vkept[folded + 7];
          ulonglong2 v0, v1, v2, v3, v4, v5, v6, v7;
#define ROWP(g) (((const ulonglong2*)(mask + (size_t)(g) * 128))[lane])
          if (0 < m) v0 = ROWP(g0);
          if (1 < m) v1 = ROWP(g1);
          if (2 < m) v2 = ROWP(g2);
          if (3 < m) v3 = ROWP(g3);
          if (4 < m) v4 = ROWP(g4);
          if (5 < m) v5 = ROWP(g5);
          if (6 < m) v6 = ROWP(g6);
          if (7 < m) v7 = ROWP(g7);
#undef ROWP
          if (0 < m) { own0 |= v0.x; own1 |= v0.y; }
          if (1 < m) { own0 |= v1.x; own1 |= v1.y; }
          if (2 < m) { own0 |= v2.x; own1 |= v2.y; }
          if (3 < m) { own0 |= v3.x; own1 |= v3.y; }
          if (4 < m) { own0 |= v4.x; own1 |= v4.y; }
          if (5 < m) { own0 |= v5.x; own1 |= v5.y; }
          if (6 < m) { own0 |= v6.x; own1 |= v6.y; }
          if (7 < m) { own0 |= v7.x; own1 |= v7.y; }
          folded += m;
        }
        if (done == 0x7F) { finished = true; break; }
        if (done == p + 1) break;  // panel p complete & fully folded
        __builtin_amdgcn_s_sleep(1);
      }
      if (finished) return;
      // publish rv for panel p+1 (words 8(p+1)..8(p+1)+7 live in lanes 4(p+1)..+3)
      int q = p + 1;
      WAITVM0();  // slab q resident before prep (wave0 reads it immediately)
      if ((lane >> 2) == q) {
        vrv[2 * (lane & 3)] = own0;
        vrv[2 * (lane & 3) + 1] = own1;
      }
      __threadfence_block();
      if (lane == 0) vctl[2] = q + 1;
    }
    return;
  }

  // ================= wave 0: scanner =================
  int cnt = 0;
  for (int p = 0; p < NPANEL; ++p) {
    while (vctl[2] < p + 1) __builtin_amdgcn_s_sleep(1);
    __threadfence_block();
    u64 remv = vrv[lane & 7];  // distributed: lane mirrors panel word lane&7
    u64 cur = vrv[0];
    const u64* sl = &slab[p & 1][0];
    int base = p * PANW;
    int w = 0;

    while (cnt < PAD) {
      u64 inv = ~cur;
      if (inv == 0ull) {  // word exhausted
        if (++w == 8) break;
        cur = __shfl(remv, w);
        continue;
      }
      int b1 = __ffsll(inv) - 1;
      u64 inv2 = inv & (inv - 1);
      int li1 = (w << 6) + b1;
      int b2 = inv2 ? (__ffsll(inv2) - 1) : -1;
      int li2 = inv2 ? ((w << 6) + b2) : li1;
      u64 mA = sl[li1 * 8 + w];           // broadcast (chain)
      u64 mB = sl[li2 * 8 + w];           // speculative, same window
      u64 sA = sl[li1 * 8 + (lane & 7)];  // per-lane-group
      u64 sB = sl[li2 * 8 + (lane & 7)];
      if (lane == 0) vkept[cnt] = base + li1;
      __threadfence_block();
      if (lane == 0) vctl[0] = cnt + 1;
      cnt++;
      cur |= mA | (1ull << b1);
      remv |= sA;
      if (b2 >= 0 && cnt < PAD && !((mA >> b2) & 1ull)) {  // spec success
        if (lane == 0) vkept[cnt] = base + li2;
        __threadfence_block();
        if (lane == 0) vctl[0] = cnt + 1;
        cnt++;
        cur |= mB | (1ull << b2);
        remv |= sB;
      }
    }
    bool finished = (cnt >= PAD) || (p == NPANEL - 1);
    __threadfence_block();
    if (lane == 0) vctl[1] = finished ? 0x7F : (p + 1);
    if (finished) break;
  }
  // epilogue
  for (int k = lane; k < cnt; k += 64) kept[k] = keptGi[k];
  if (lane == 0) *num_kept = cnt;
}

// ---------------- K5: gather outputs ----------------
__global__ __launch_bounds__(128) void gather_kernel(
    const int* __restrict__ kept, const int* __restrict__ num_kept_p,
    const int* __restrict__ sortedIdx, const float4* __restrict__ sortedBoxes,
    const float* __restrict__ scores, float* __restrict__ out) {
  int r = blockIdx.x;  // 0..299
  int t = threadIdx.x;
  float* boxes_out = out;             // (300,4)
  float* scores_out = out + PAD * 4;  // (300,81)
  int nk = *num_kept_p;
  bool valid = r < nk;
  int pos = valid ? kept[r] : 0;
  if (t < NCLS) {
    int orig = sortedIdx[pos];
    scores_out[(size_t)r * NCLS + t] = valid ? scores[(size_t)orig * NCLS + t] : 0.0f;
  }
  if (t == 96) {
    float4 b = sortedBoxes[pos];
    if (!valid) b = make_float4(0.f, 0.f, 0.f, 0.f);
    ((float4*)boxes_out)[r] = b;
  }
}

extern "C" void kernel_launch(void* const* d_in, const int* in_sizes, int n_in,
                              void* d_out, int out_size, void* d_ws, size_t ws_size,
                              hipStream_t stream) {
  const float* meta = (const float*)d_in[0];
  const float* deltas = (const float*)d_in[1];
  const float* proposals = (const float*)d_in[2];
  const float* scores = (const float*)d_in[3];
  float* out = (float*)d_out;
  char* ws = (char*)d_ws;

  float4* sel = (float4*)(ws + 0);               // 131072 B
  u64* keys = (u64*)(ws + 131072);               // 65536 B
  int* rank = (int*)(ws + 196608);               // 32768 B
  int* sortedIdx = (int*)(ws + 229376);          // 32768 B
  float4* sortedBoxes = (float4*)(ws + 262144);  // 131072 B
  int* kept = (int*)(ws + 393216);               // 1200 B
  int* num_kept = (int*)(ws + 395264);           // 4 B
  u64* mask = (u64*)(ws + 409600);               // 8 MiB row-major

  decode_kernel<<<N / 32, 256, 0, stream>>>(meta, deltas, proposals, scores, sel, keys, rank);
  rank_kernel<<<dim3(N / 256, N / 256), 256, 0, stream>>>(keys, rank);
  scatter_kernel<<<N / 256, 256, 0, stream>>>(rank, sel, sortedIdx, sortedBoxes);
  mask_kernel<<<dim3(N / 128, N / 256), 256, 0, stream>>>(sortedBoxes, mask);
  nms_scan_kernel<<<1, 128, 0, stream>>>(mask, kept, num_kept);
  gather_kernel<<<PAD, 128, 0, stream>>>(kept, num_kept, sortedIdx, sortedBoxes, scores, out);
}

// Round 13
// 118.309 us; speedup vs baseline: 1.0494x; 1.0494x over previous
//
#include <hip/hip_runtime.h>

#define N 8192
#define NCLS 81
#define PAD 300
#define NPANEL 16
#define PANW 512

typedef unsigned long long u64;

__device__ __forceinline__ void gload_lds16(const void* g, void* l) {
  __builtin_amdgcn_global_load_lds(
      (const __attribute__((address_space(1))) unsigned int*)g,
      (__attribute__((address_space(3))) unsigned int*)l, 16, 0, 0);
}

// ---------------- K1: decode, 8 lanes per row (coalesced 32B segments) ----------------
__global__ __launch_bounds__(256) void decode_kernel(
    const float* __restrict__ meta, const float* __restrict__ deltas,
    const float* __restrict__ proposals, const float* __restrict__ scores,
    float4* __restrict__ sel, u64* __restrict__ keys, int* __restrict__ rank) {
  int tid = threadIdx.x;
  int row = blockIdx.x * 32 + (tid >> 3);
  int sub = tid & 7;
  const float* srow = scores + (size_t)row * NCLS;
  float bs = -1e30f, ms = -1e30f;
  int best = 0;
  for (int c = sub; c < NCLS; c += 8) {
    float v = srow[c];
    if (v > bs) { bs = v; best = c; }  // ascending c: local first-max
    if (c > 0) ms = fmaxf(ms, v);
  }
  // 8-lane reduce: (max val, min class idx on ties) == global first-max (jnp.argmax)
#pragma unroll
  for (int d = 1; d < 8; d <<= 1) {
    float ob = __shfl_xor(bs, d);
    int oi = __shfl_xor(best, d);
    float om = __shfl_xor(ms, d);
    if (ob > bs || (ob == bs && oi < best)) { bs = ob; best = oi; }
    ms = fmaxf(ms, om);
  }
  if (sub == 0) {
    float W = meta[1], sc = meta[2], H = meta[0];
    const float* p = proposals + row * 4;
    float x1 = p[0] / sc, y1 = p[1] / sc, x2 = p[2] / sc, y2 = p[3] / sc;
    float w = x2 - x1 + 1.0f, h = y2 - y1 + 1.0f;
    float cx = x1 + 0.5f * w, cy = y1 + 0.5f * h;
    float4 d4 = *(const float4*)(deltas + (size_t)row * (4 * NCLS) + best * 4);  // 16B aligned
    float pcx = d4.x * w + cx, pcy = d4.y * h + cy;
    float pw = expf(d4.z) * w, ph = expf(d4.w) * h;
    float lx = W - 1.0f, ly = H - 1.0f;
    float ox1 = fminf(fmaxf(pcx - 0.5f * pw, 0.0f), lx);
    float oy1 = fminf(fmaxf(pcy - 0.5f * ph, 0.0f), ly);
    float ox2 = fminf(fmaxf(pcx + 0.5f * pw, 0.0f), lx);
    float oy2 = fminf(fmaxf(pcy + 0.5f * ph, 0.0f), ly);
    sel[row] = make_float4(ox1, oy1, ox2, oy2);
    keys[row] = ((u64)(~__float_as_uint(ms)) << 32) | (unsigned)row;
    rank[row] = 0;
  }
}

// ---------------- K2a: brute-force rank, LDS-tiled (stable sort of unique keys) ------
__global__ __launch_bounds__(256) void rank_kernel(
    const u64* __restrict__ keys, int* __restrict__ rank) {
  __shared__ u64 kt[256];
  int tid = threadIdx.x;
  int i = blockIdx.x * 256 + tid;
  kt[tid] = keys[blockIdx.y * 256 + tid];
  u64 ki = keys[i];
  __syncthreads();
  int c = 0;
#pragma unroll 8
  for (int t = 0; t < 256; ++t) c += (kt[t] < ki);
  atomicAdd(&rank[i], c);
}

// ---------------- K2b: scatter into sorted order ----------------
__global__ __launch_bounds__(256) void scatter_kernel(
    const int* __restrict__ rank, const float4* __restrict__ sel,
    int* __restrict__ sortedIdx, float4* __restrict__ sortedBoxes) {
  int i = blockIdx.x * 256 + threadIdx.x;
  int r = rank[i];
  sortedIdx[r] = i;
  sortedBoxes[r] = sel[i];
}

// ---------------- K3: suppression bitmask — occupancy-first tiling (R10 proven) ------
__global__ __launch_bounds__(256) void mask_kernel(
    const float4* __restrict__ boxes, u64* __restrict__ mask) {
  int q = blockIdx.x;   // col-group of 128
  int ry = blockIdx.y;  // row-group of 256
  int jbase = q * 128, rbase = ry * 256;
  if (jbase + 128 <= rbase) return;  // strictly lower-tri block
  __shared__ float4 cbox[128];
  __shared__ float carea[128];
  int tid = threadIdx.x;
  if (tid < 128) {
    float4 b = boxes[jbase + tid];
    cbox[tid] = b;
    carea[tid] = fmaxf(b.z - b.x, 0.0f) * fmaxf(b.w - b.y, 0.0f);
  }
  __syncthreads();
  int r = rbase + tid;
  int rel = r - jbase;      // bits valid only for cc > rel
  if (rel >= 128) return;   // both words strictly lower-tri: stay poison (never read)
  float4 bi = boxes[r];
  float areaA = fmaxf(bi.z - bi.x, 0.0f) * fmaxf(bi.w - bi.y, 0.0f);
  u64 out2[2];
#pragma unroll
  for (int w = 0; w < 2; ++w) {
    unsigned lo = 0, hi = 0;
#pragma unroll 16
    for (int c = 0; c < 64; ++c) {
      int cc = (w << 6) + c;
      float4 bj = cbox[cc];
      float lxv = fmaxf(bi.x, bj.x), lyv = fmaxf(bi.y, bj.y);
      float rxv = fminf(bi.z, bj.z), ryv = fminf(bi.w, bj.w);
      float iw = fmaxf(rxv - lxv, 0.0f), ih = fmaxf(ryv - lyv, 0.0f);
      float inter = iw * ih;
      float u = areaA + carea[cc] - inter + 1e-8f;  // exact ref assoc order
      float sA = inter * 33554432.0f;  // * 2^25, exact
      float sB = u * 16777216.0f;      // * 2^24, exact
      unsigned sup = (((sA - sB) - u) > 0.0f) ? 1u : 0u;
      if (c < 32) lo |= sup << c; else hi |= sup << (c - 32);
    }
    u64 bits = ((u64)hi << 32) | lo;
    int relw = rel - (w << 6);            // need c > relw within this word
    if (relw >= 63) bits = 0ull;
    else if (relw >= 0) bits &= ~((1ull << (relw + 1)) - 1ull);
    out2[w] = bits;
  }
  *(ulonglong2*)(mask + (size_t)r * 128 + q * 2) = make_ulonglong2(out2[0], out2[1]);
}

// ---------------- K4: serial greedy scan — R6 keep-loop + entry-gather (no fold) ------
// Keep-loop is R6 verbatim (proven 49.4µs; no VM ops / sync / fences in chain).
// The per-panel-exit incremental fold (own0/own1, ~20µs serial L3 batches) is
// replaced by a panel-ENTRY full-ILP gather: remv word (lane&7) = OR over ALL
// keeps so far of mask[keptRow][8p + (lane&7)] — every load independent, one
// latency window. Gather rows are strictly above panel p (row < 64*8p) =>
// always-computed words (never poison). One manual vmcnt(0)+sched_barrier per
// panel covers both slab-p residency and gather completion; slab p+1 copy is
// issued at entry and overlaps the whole in-panel scan.
__global__ __launch_bounds__(64) void nms_scan_kernel(
    const u64* __restrict__ mask, int* __restrict__ kept, int* __restrict__ num_kept) {
  __shared__ u64 slab[2][PANW * 8];  // 2 x 32 KiB double-buffered diagonal slabs
  __shared__ int keptGi[PAD];        // global (sorted) indices of keeps
  int lane = threadIdx.x;
  int cnt = 0;
  const char* mb = (const char*)mask;

  // prologue: issue slab copy for panel 0
#pragma unroll
  for (int it = 0; it < 32; ++it) {
    const char* g = mb + (size_t)(it * 16 + (lane >> 2)) * 1024 + (lane & 3) * 16;
    gload_lds16(g, &slab[0][0] + it * 128);
  }

  for (int p = 0; p < NPANEL; ++p) {
    int base = p * PANW;
    const u64* sl = &slab[p & 1][0];

    // entry gather: all keeps in flight at once (full ILP, one latency window)
    u64 acc = 0ull;
    for (int k = (lane >> 3); k < cnt; k += 8)
      acc |= mask[(size_t)keptGi[k] * 128 + p * 8 + (lane & 7)];

    asm volatile("s_waitcnt vmcnt(0)" ::: "memory");  // slab p resident + gather done
    __builtin_amdgcn_sched_barrier(0);

    acc |= __shfl_xor(acc, 8);
    acc |= __shfl_xor(acc, 16);
    acc |= __shfl_xor(acc, 32);  // every lane: full remv word (lane&7)

    // issue slab copy for panel p+1 (overlaps the entire in-panel scan)
    if (p < NPANEL - 1) {
      u64* dst = &slab[(p + 1) & 1][0];
      const char* srcB = mb + (size_t)(base + PANW) * 1024 + (size_t)(p + 1) * 64;
#pragma unroll
      for (int it = 0; it < 32; ++it) {
        const char* g = srcB + (size_t)(it * 16 + (lane >> 2)) * 1024 + (lane & 3) * 16;
        gload_lds16(g, dst + it * 128);
      }
    }

    // replicate the 8 panel words into named regs (word advance = register move)
    u64 rv0 = __shfl(acc, 0), rv1 = __shfl(acc, 1);
    u64 rv2 = __shfl(acc, 2), rv3 = __shfl(acc, 3);
    u64 rv4 = __shfl(acc, 4), rv5 = __shfl(acc, 5);
    u64 rv6 = __shfl(acc, 6), rv7 = __shfl(acc, 7);
    int w = 0;
    u64 cur = rv0;

    // ---- R6 keep-loop verbatim (pure LDS+VALU, spec-2) ----
    while (cnt < PAD) {
      u64 inv = ~cur;
      if (inv == 0ull) {  // word exhausted
        if (++w == 8) break;
        cur = (w == 1) ? rv1 : (w == 2) ? rv2 : (w == 3) ? rv3 : (w == 4) ? rv4
            : (w == 5) ? rv5 : (w == 6) ? rv6 : rv7;
        continue;
      }
      int b1 = __ffsll(inv) - 1;
      u64 inv2 = inv & (inv - 1);
      int li1 = (w << 6) + b1;
      int b2 = inv2 ? (__ffsll(inv2) - 1) : -1;
      int li2 = inv2 ? ((w << 6) + b2) : li1;
      const u64* rA = sl + li1 * 8;
      const u64* rB = sl + li2 * 8;
      u64 mA = rA[w];  // dependent hop (chain)
      u64 mB = rB[w];  // speculative, same latency window
      ulonglong2 a0 = ((const ulonglong2*)rA)[0], a1 = ((const ulonglong2*)rA)[1];
      ulonglong2 a2 = ((const ulonglong2*)rA)[2], a3 = ((const ulonglong2*)rA)[3];
      if (lane == 0) kept[cnt] = base + li1;
      keptGi[cnt] = base + li1;
      cnt++;
      cur |= mA | (1ull << b1);
      rv0 |= a0.x; rv1 |= a0.y; rv2 |= a1.x; rv3 |= a1.y;
      rv4 |= a2.x; rv5 |= a2.y; rv6 |= a3.x; rv7 |= a3.y;
      if (b2 >= 0 && cnt < PAD && !((mA >> b2) & 1ull)) {  // speculation success
        ulonglong2 c0 = ((const ulonglong2*)rB)[0], c1 = ((const ulonglong2*)rB)[1];
        ulonglong2 c2 = ((const ulonglong2*)rB)[2], c3 = ((const ulonglong2*)rB)[3];
        if (lane == 0) kept[cnt] = base + li2;
        keptGi[cnt] = base + li2;
        cnt++;
        cur |= mB | (1ull << b2);
        rv0 |= c0.x; rv1 |= c0.y; rv2 |= c1.x; rv3 |= c1.y;
        rv4 |= c2.x; rv5 |= c2.y; rv6 |= c3.x; rv7 |= c3.y;
      }
    }
    if (cnt >= PAD) break;
  }
  if (lane == 0) *num_kept = cnt;
}

// ---------------- K5: gather outputs ----------------
__global__ __launch_bounds__(128) void gather_kernel(
    const int* __restrict__ kept, const int* __restrict__ num_kept_p,
    const int* __restrict__ sortedIdx, const float4* __restrict__ sortedBoxes,
    const float* __restrict__ scores, float* __restrict__ out) {
  int r = blockIdx.x;  // 0..299
  int t = threadIdx.x;
  float* boxes_out = out;             // (300,4)
  float* scores_out = out + PAD * 4;  // (300,81)
  int nk = *num_kept_p;
  bool valid = r < nk;
  int pos = valid ? kept[r] : 0;
  if (t < NCLS) {
    int orig = sortedIdx[pos];
    scores_out[(size_t)r * NCLS + t] = valid ? scores[(size_t)orig * NCLS + t] : 0.0f;
  }
  if (t == 96) {
    float4 b = sortedBoxes[pos];
    if (!valid) b = make_float4(0.f, 0.f, 0.f, 0.f);
    ((float4*)boxes_out)[r] = b;
  }
}

extern "C" void kernel_launch(void* const* d_in, const int* in_sizes, int n_in,
                              void* d_out, int out_size, void* d_ws, size_t ws_size,
                              hipStream_t stream) {
  const float* meta = (const float*)d_in[0];
  const float* deltas = (const float*)d_in[1];
  const float* proposals = (const float*)d_in[2];
  const float* scores = (const float*)d_in[3];
  float* out = (float*)d_out;
  char* ws = (char*)d_ws;

  float4* sel = (float4*)(ws + 0);               // 131072 B
  u64* keys = (u64*)(ws + 131072);               // 65536 B
  int* rank = (int*)(ws + 196608);               // 32768 B
  int* sortedIdx = (int*)(ws + 229376);          // 32768 B
  float4* sortedBoxes = (float4*)(ws + 262144);  // 131072 B
  int* kept = (int*)(ws + 393216);               // 1200 B
  int* num_kept = (int*)(ws + 395264);           // 4 B
  u64* mask = (u64*)(ws + 409600);               // 8 MiB row-major

  decode_kernel<<<N / 32, 256, 0, stream>>>(meta, deltas, proposals, scores, sel, keys, rank);
  rank_kernel<<<dim3(N / 256, N / 256), 256, 0, stream>>>(keys, rank);
  scatter_kernel<<<N / 256, 256, 0, stream>>>(rank, sel, sortedIdx, sortedBoxes);
  mask_kernel<<<dim3(N / 128, N / 256), 256, 0, stream>>>(sortedBoxes, mask);
  nms_scan_kernel<<<1, 64, 0, stream>>>(mask, kept, num_kept);
  gather_kernel<<<PAD, 128, 0, stream>>>(kept, num_kept, sortedIdx, sortedBoxes, scores, out);
}

// Round 14
// 116.767 us; speedup vs baseline: 1.0633x; 1.0132x over previous
//
#include <hip/hip_runtime.h>

#define N 8192
#define NCLS 81
#define PAD 300
#define NPANEL 16
#define PANW 512

typedef unsigned long long u64;

__device__ __forceinline__ void gload_lds16(const void* g, void* l) {
  __builtin_amdgcn_global_load_lds(
      (const __attribute__((address_space(1))) unsigned int*)g,
      (__attribute__((address_space(3))) unsigned int*)l, 16, 0, 0);
}

// ---------------- K1: decode, 8 lanes per row (coalesced 32B segments) ----------------
__global__ __launch_bounds__(256) void decode_kernel(
    const float* __restrict__ meta, const float* __restrict__ deltas,
    const float* __restrict__ proposals, const float* __restrict__ scores,
    float4* __restrict__ sel, u64* __restrict__ keys, int* __restrict__ rank) {
  int tid = threadIdx.x;
  int row = blockIdx.x * 32 + (tid >> 3);
  int sub = tid & 7;
  const float* srow = scores + (size_t)row * NCLS;
  float bs = -1e30f, ms = -1e30f;
  int best = 0;
  for (int c = sub; c < NCLS; c += 8) {
    float v = srow[c];
    if (v > bs) { bs = v; best = c; }  // ascending c: local first-max
    if (c > 0) ms = fmaxf(ms, v);
  }
  // 8-lane reduce: (max val, min class idx on ties) == global first-max (jnp.argmax)
#pragma unroll
  for (int d = 1; d < 8; d <<= 1) {
    float ob = __shfl_xor(bs, d);
    int oi = __shfl_xor(best, d);
    float om = __shfl_xor(ms, d);
    if (ob > bs || (ob == bs && oi < best)) { bs = ob; best = oi; }
    ms = fmaxf(ms, om);
  }
  if (sub == 0) {
    float W = meta[1], sc = meta[2], H = meta[0];
    const float* p = proposals + row * 4;
    float x1 = p[0] / sc, y1 = p[1] / sc, x2 = p[2] / sc, y2 = p[3] / sc;
    float w = x2 - x1 + 1.0f, h = y2 - y1 + 1.0f;
    float cx = x1 + 0.5f * w, cy = y1 + 0.5f * h;
    float4 d4 = *(const float4*)(deltas + (size_t)row * (4 * NCLS) + best * 4);  // 16B aligned
    float pcx = d4.x * w + cx, pcy = d4.y * h + cy;
    float pw = expf(d4.z) * w, ph = expf(d4.w) * h;
    float lx = W - 1.0f, ly = H - 1.0f;
    float ox1 = fminf(fmaxf(pcx - 0.5f * pw, 0.0f), lx);
    float oy1 = fminf(fmaxf(pcy - 0.5f * ph, 0.0f), ly);
    float ox2 = fminf(fmaxf(pcx + 0.5f * pw, 0.0f), lx);
    float oy2 = fminf(fmaxf(pcy + 0.5f * ph, 0.0f), ly);
    sel[row] = make_float4(ox1, oy1, ox2, oy2);
    keys[row] = ((u64)(~__float_as_uint(ms)) << 32) | (unsigned)row;
    rank[row] = 0;
  }
}

// ---------------- K2a: brute-force rank, LDS-tiled (stable sort of unique keys) ------
__global__ __launch_bounds__(256) void rank_kernel(
    const u64* __restrict__ keys, int* __restrict__ rank) {
  __shared__ u64 kt[256];
  int tid = threadIdx.x;
  int i = blockIdx.x * 256 + tid;
  kt[tid] = keys[blockIdx.y * 256 + tid];
  u64 ki = keys[i];
  __syncthreads();
  int c = 0;
#pragma unroll 8
  for (int t = 0; t < 256; ++t) c += (kt[t] < ki);
  atomicAdd(&rank[i], c);
}

// ---------------- K2b: scatter into sorted order ----------------
__global__ __launch_bounds__(256) void scatter_kernel(
    const int* __restrict__ rank, const float4* __restrict__ sel,
    int* __restrict__ sortedIdx, float4* __restrict__ sortedBoxes) {
  int i = blockIdx.x * 256 + threadIdx.x;
  int r = rank[i];
  sortedIdx[r] = i;
  sortedBoxes[r] = sel[i];
}

// ---------------- K3: suppression bitmask — occupancy-first tiling (R10 proven) ------
__global__ __launch_bounds__(256) void mask_kernel(
    const float4* __restrict__ boxes, u64* __restrict__ mask) {
  int q = blockIdx.x;   // col-group of 128
  int ry = blockIdx.y;  // row-group of 256
  int jbase = q * 128, rbase = ry * 256;
  if (jbase + 128 <= rbase) return;  // strictly lower-tri block
  __shared__ float4 cbox[128];
  __shared__ float carea[128];
  int tid = threadIdx.x;
  if (tid < 128) {
    float4 b = boxes[jbase + tid];
    cbox[tid] = b;
    carea[tid] = fmaxf(b.z - b.x, 0.0f) * fmaxf(b.w - b.y, 0.0f);
  }
  __syncthreads();
  int r = rbase + tid;
  int rel = r - jbase;      // bits valid only for cc > rel
  if (rel >= 128) return;   // both words strictly lower-tri: stay poison (never read)
  float4 bi = boxes[r];
  float areaA = fmaxf(bi.z - bi.x, 0.0f) * fmaxf(bi.w - bi.y, 0.0f);
  u64 out2[2];
#pragma unroll
  for (int w = 0; w < 2; ++w) {
    unsigned lo = 0, hi = 0;
#pragma unroll 16
    for (int c = 0; c < 64; ++c) {
      int cc = (w << 6) + c;
      float4 bj = cbox[cc];
      float lxv = fmaxf(bi.x, bj.x), lyv = fmaxf(bi.y, bj.y);
      float rxv = fminf(bi.z, bj.z), ryv = fminf(bi.w, bj.w);
      float iw = fmaxf(rxv - lxv, 0.0f), ih = fmaxf(ryv - lyv, 0.0f);
      float inter = iw * ih;
      float u = areaA + carea[cc] - inter + 1e-8f;  // exact ref assoc order
      float sA = inter * 33554432.0f;  // * 2^25, exact
      float sB = u * 16777216.0f;      // * 2^24, exact
      unsigned sup = (((sA - sB) - u) > 0.0f) ? 1u : 0u;
      if (c < 32) lo |= sup << c; else hi |= sup << (c - 32);
    }
    u64 bits = ((u64)hi << 32) | lo;
    int relw = rel - (w << 6);            // need c > relw within this word
    if (relw >= 63) bits = 0ull;
    else if (relw >= 0) bits &= ~((1ull << (relw + 1)) - 1ull);
    out2[w] = bits;
  }
  *(ulonglong2*)(mask + (size_t)r * 128 + q * 2) = make_ulonglong2(out2[0], out2[1]);
}

// ---------------- K4: serial greedy scan — spec-4, distributed remv ----------------
// Structure: R12's entry-gather + slab-prefetch (proven); keep-loop upgraded:
// (a) 4-way speculation: 4 candidate bits per iteration, 8 independent
//     ds_read_b64 in one latency window, validity resolved by register bit
//     tests (suppressed candidates' bits are covered by the suppressor's mA);
// (b) distributed panel-remv (lane holds word lane&7; one sA b64 per keep
//     replaces 4x b128 replication; word advance = 1 shfl, 8/panel).
// No VM ops / fences / cross-wave sync in the chain (R5/R7/R11 lessons).
// Poison: sA reads of words < current word land in remv words never re-read;
// gather rows strictly upper-tri; candidate mA words are diagonal-computed.
__global__ __launch_bounds__(64) void nms_scan_kernel(
    const u64* __restrict__ mask, int* __restrict__ kept, int* __restrict__ num_kept) {
  __shared__ u64 slab[2][PANW * 8];  // 2 x 32 KiB double-buffered diagonal slabs
  __shared__ int keptGi[PAD];        // global (sorted) indices of keeps
  int lane = threadIdx.x;
  int cnt = 0;
  const char* mb = (const char*)mask;

  // prologue: issue slab copy for panel 0
#pragma unroll
  for (int it = 0; it < 32; ++it) {
    const char* g = mb + (size_t)(it * 16 + (lane >> 2)) * 1024 + (lane & 3) * 16;
    gload_lds16(g, &slab[0][0] + it * 128);
  }

  for (int p = 0; p < NPANEL; ++p) {
    int base = p * PANW;
    const u64* sl = &slab[p & 1][0];

    // entry gather: all keeps in flight at once (full ILP, one latency window)
    u64 acc = 0ull;
    for (int k = (lane >> 3); k < cnt; k += 8)
      acc |= mask[(size_t)keptGi[k] * 128 + p * 8 + (lane & 7)];

    asm volatile("s_waitcnt vmcnt(0)" ::: "memory");  // slab p resident + gather done
    __builtin_amdgcn_sched_barrier(0);

    acc |= __shfl_xor(acc, 8);
    acc |= __shfl_xor(acc, 16);
    acc |= __shfl_xor(acc, 32);
    u64 remv = acc;             // lane holds panel word (lane&7)
    u64 cur = __shfl(remv, 0);  // word 0 broadcast

    // issue slab copy for panel p+1 (overlaps the entire in-panel scan)
    if (p < NPANEL - 1) {
      u64* dst = &slab[(p + 1) & 1][0];
      const char* srcB = mb + (size_t)(base + PANW) * 1024 + (size_t)(p + 1) * 64;
#pragma unroll
      for (int it = 0; it < 32; ++it) {
        const char* g = srcB + (size_t)(it * 16 + (lane >> 2)) * 1024 + (lane & 3) * 16;
        gload_lds16(g, dst + it * 128);
      }
    }

    int w = 0;
    while (cnt < PAD) {
      u64 inv = ~cur;
      if (inv == 0ull) {  // word exhausted
        if (++w == 8) break;
        cur = __shfl(remv, w);
        continue;
      }
      // up to 4 candidate bits
      int b1 = __ffsll(inv) - 1;
      u64 i2 = inv & (inv - 1);
      int b2 = i2 ? (__ffsll(i2) - 1) : -1;
      u64 i3 = i2 ? (i2 & (i2 - 1)) : 0ull;
      int b3 = i3 ? (__ffsll(i3) - 1) : -1;
      u64 i4 = i3 ? (i3 & (i3 - 1)) : 0ull;
      int b4 = i4 ? (__ffsll(i4) - 1) : -1;
      int li1 = (w << 6) + b1;
      int li2 = (b2 >= 0) ? ((w << 6) + b2) : li1;
      int li3 = (b3 >= 0) ? ((w << 6) + b3) : li1;
      int li4 = (b4 >= 0) ? ((w << 6) + b4) : li1;
      // 8 independent ds_read_b64 — one latency window
      u64 mA1 = sl[li1 * 8 + w], sA1 = sl[li1 * 8 + (lane & 7)];
      u64 mA2 = sl[li2 * 8 + w], sA2 = sl[li2 * 8 + (lane & 7)];
      u64 mA3 = sl[li3 * 8 + w], sA3 = sl[li3 * 8 + (lane & 7)];
      u64 mA4 = sl[li4 * 8 + w], sA4 = sl[li4 * 8 + (lane & 7)];
      // resolve validity (register-only; suppressed bits covered by suppressor mA)
      bool k2 = (b2 >= 0) && !((mA1 >> b2) & 1ull);
      bool k3 = (b3 >= 0) && !((mA1 >> b3) & 1ull) && !(k2 && ((mA2 >> b3) & 1ull));
      bool k4 = (b4 >= 0) && !((mA1 >> b4) & 1ull) && !(k2 && ((mA2 >> b4) & 1ull)) &&
                !(k3 && ((mA3 >> b4) & 1ull));
      // commit sequentially with PAD guard
      if (lane == 0) kept[cnt] = base + li1;
      keptGi[cnt] = base + li1;
      cnt++;
      cur |= mA1 | (1ull << b1);
      remv |= sA1;
      if (cnt >= PAD) break;
      if (k2) {
        if (lane == 0) kept[cnt] = base + li2;
        keptGi[cnt] = base + li2;
        cnt++;
        cur |= mA2 | (1ull << b2);
        remv |= sA2;
        if (cnt >= PAD) break;
      }
      if (k3) {
        if (lane == 0) kept[cnt] = base + li3;
        keptGi[cnt] = base + li3;
        cnt++;
        cur |= mA3 | (1ull << b3);
        remv |= sA3;
        if (cnt >= PAD) break;
      }
      if (k4) {
        if (lane == 0) kept[cnt] = base + li4;
        keptGi[cnt] = base + li4;
        cnt++;
        cur |= mA4 | (1ull << b4);
        remv |= sA4;
        if (cnt >= PAD) break;
      }
    }
    if (cnt >= PAD) break;
  }
  if (lane == 0) *num_kept = cnt;
}

// ---------------- K5: gather outputs ----------------
__global__ __launch_bounds__(128) void gather_kernel(
    const int* __restrict__ kept, const int* __restrict__ num_kept_p,
    const int* __restrict__ sortedIdx, const float4* __restrict__ sortedBoxes,
    const float* __restrict__ scores, float* __restrict__ out) {
  int r = blockIdx.x;  // 0..299
  int t = threadIdx.x;
  float* boxes_out = out;             // (300,4)
  float* scores_out = out + PAD * 4;  // (300,81)
  int nk = *num_kept_p;
  bool valid = r < nk;
  int pos = valid ? kept[r] : 0;
  if (t < NCLS) {
    int orig = sortedIdx[pos];
    scores_out[(size_t)r * NCLS + t] = valid ? scores[(size_t)orig * NCLS + t] : 0.0f;
  }
  if (t == 96) {
    float4 b = sortedBoxes[pos];
    if (!valid) b = make_float4(0.f, 0.f, 0.f, 0.f);
    ((float4*)boxes_out)[r] = b;
  }
}

extern "C" void kernel_launch(void* const* d_in, const int* in_sizes, int n_in,
                              void* d_out, int out_size, void* d_ws, size_t ws_size,
                              hipStream_t stream) {
  const float* meta = (const float*)d_in[0];
  const float* deltas = (const float*)d_in[1];
  const float* proposals = (const float*)d_in[2];
  const float* scores = (const float*)d_in[3];
  float* out = (float*)d_out;
  char* ws = (char*)d_ws;

  float4* sel = (float4*)(ws + 0);               // 131072 B
  u64* keys = (u64*)(ws + 131072);               // 65536 B
  int* rank = (int*)(ws + 196608);               // 32768 B
  int* sortedIdx = (int*)(ws + 229376);          // 32768 B
  float4* sortedBoxes = (float4*)(ws + 262144);  // 131072 B
  int* kept = (int*)(ws + 393216);               // 1200 B
  int* num_kept = (int*)(ws + 395264);           // 4 B
  u64* mask = (u64*)(ws + 409600);               // 8 MiB row-major

  decode_kernel<<<N / 32, 256, 0, stream>>>(meta, deltas, proposals, scores, sel, keys, rank);
  rank_kernel<<<dim3(N / 256, N / 256), 256, 0, stream>>>(keys, rank);
  scatter_kernel<<<N / 256, 256, 0, stream>>>(rank, sel, sortedIdx, sortedBoxes);
  mask_kernel<<<dim3(N / 128, N / 256), 256, 0, stream>>>(sortedBoxes, mask);
  nms_scan_kernel<<<1, 64, 0, stream>>>(mask, kept, num_kept);
  gather_kernel<<<PAD, 128, 0, stream>>>(kept, num_kept, sortedIdx, sortedBoxes, scores, out);
}

// Round 15
// 103.646 us; speedup vs baseline: 1.1979x; 1.1266x over previous
//
#include <hip/hip_runtime.h>

#define N 8192
#define NCLS 81
#define PAD 300
#define NPANEL 16
#define PANW 512

typedef unsigned long long u64;

__device__ __forceinline__ void gload_lds16(const void* g, void* l) {
  __builtin_amdgcn_global_load_lds(
      (const __attribute__((address_space(1))) unsigned int*)g,
      (__attribute__((address_space(3))) unsigned int*)l, 16, 0, 0);
}

// ---------------- K1: decode, 8 lanes per row + ctr/rank zero ----------------
__global__ __launch_bounds__(256) void decode_kernel(
    const float* __restrict__ meta, const float* __restrict__ deltas,
    const float* __restrict__ proposals, const float* __restrict__ scores,
    float4* __restrict__ sel, u64* __restrict__ keys, int* __restrict__ rank,
    int* __restrict__ ctr) {
  int tid = threadIdx.x;
  if (blockIdx.x == 0 && tid < 16) ctr[tid] = 0;  // col-panel counters
  int row = blockIdx.x * 32 + (tid >> 3);
  int sub = tid & 7;
  const float* srow = scores + (size_t)row * NCLS;
  float bs = -1e30f, ms = -1e30f;
  int best = 0;
  for (int c = sub; c < NCLS; c += 8) {
    float v = srow[c];
    if (v > bs) { bs = v; best = c; }
    if (c > 0) ms = fmaxf(ms, v);
  }
#pragma unroll
  for (int d = 1; d < 8; d <<= 1) {
    float ob = __shfl_xor(bs, d);
    int oi = __shfl_xor(best, d);
    float om = __shfl_xor(ms, d);
    if (ob > bs || (ob == bs && oi < best)) { bs = ob; best = oi; }
    ms = fmaxf(ms, om);
  }
  if (sub == 0) {
    float W = meta[1], sc = meta[2], H = meta[0];
    const float* p = proposals + row * 4;
    float x1 = p[0] / sc, y1 = p[1] / sc, x2 = p[2] / sc, y2 = p[3] / sc;
    float w = x2 - x1 + 1.0f, h = y2 - y1 + 1.0f;
    float cx = x1 + 0.5f * w, cy = y1 + 0.5f * h;
    float4 d4 = *(const float4*)(deltas + (size_t)row * (4 * NCLS) + best * 4);
    float pcx = d4.x * w + cx, pcy = d4.y * h + cy;
    float pw = expf(d4.z) * w, ph = expf(d4.w) * h;
    float lx = W - 1.0f, ly = H - 1.0f;
    float ox1 = fminf(fmaxf(pcx - 0.5f * pw, 0.0f), lx);
    float oy1 = fminf(fmaxf(pcy - 0.5f * ph, 0.0f), ly);
    float ox2 = fminf(fmaxf(pcx + 0.5f * pw, 0.0f), lx);
    float oy2 = fminf(fmaxf(pcy + 0.5f * ph, 0.0f), ly);
    sel[row] = make_float4(ox1, oy1, ox2, oy2);
    keys[row] = ((u64)(~__float_as_uint(ms)) << 32) | (unsigned)row;
    rank[row] = 0;
  }
}

// ---------------- K2a: brute-force rank, LDS-tiled ----------------
__global__ __launch_bounds__(256) void rank_kernel(
    const u64* __restrict__ keys, int* __restrict__ rank) {
  __shared__ u64 kt[256];
  int tid = threadIdx.x;
  int i = blockIdx.x * 256 + tid;
  kt[tid] = keys[blockIdx.y * 256 + tid];
  u64 ki = keys[i];
  __syncthreads();
  int c = 0;
#pragma unroll 8
  for (int t = 0; t < 256; ++t) c += (kt[t] < ki);
  atomicAdd(&rank[i], c);
}

// ---------------- K2b: scatter into sorted order (+ exact area) ----------------
__global__ __launch_bounds__(256) void scatter_kernel(
    const int* __restrict__ rank, const float4* __restrict__ sel,
    int* __restrict__ sortedIdx, float4* __restrict__ sortedBoxes,
    float* __restrict__ sortedArea) {
  int i = blockIdx.x * 256 + threadIdx.x;
  int r = rank[i];
  float4 b = sel[i];
  sortedIdx[r] = i;
  sortedBoxes[r] = b;
  sortedArea[r] = fmaxf(b.z - b.x, 0.0f) * fmaxf(b.w - b.y, 0.0f);
}

// ---------------- K3+K4 fused: mask workers + gated greedy scan ----------------
// Block 0 = R13 scan (keep-loop verbatim; per-panel gates, half-slab pipelining).
// Blocks 1..4096 = mask workers: (cb=64-col block, rg=256-row chunk), active iff
// 4*rg <= cb. Lane = column (bj, areaB in regs); __ballot gives the u64 word.
// Visibility across XCDs without kernel boundary: agent-scope atomic stores for
// mask words (write-through), per-col-panel release atomicAdd on ctr after
// syncthreads; scan polls relaxed then acquire (invalidate) per gate — 16 total
// waits, OFF the keep chain (R5/R7/R11 lessons). Deadlock-free: workers never
// wait; ctr monotone; block 0 resident from dispatch.
// expected[cp] = 16*cp + 12 blocks (sum over cb in [8cp,8cp+8) of floor(cb/4)+1).
// Poison invariant unchanged: strictly-lower words never stored; slab copies of
// them (half-2 low words) OR into already-passed remv words only.
__global__ __launch_bounds__(256) void mask_scan_kernel(
    const float4* __restrict__ sboxes, const float* __restrict__ sarea,
    u64* __restrict__ mask, int* __restrict__ kept, int* __restrict__ num_kept,
    int* __restrict__ ctr) {
  __shared__ union {
    u64 slab[PANW * 8];                              // 32 KiB (scan)
    struct { float4 cbox[256]; float carea[256]; } m;  // 5 KiB (mask)
  } sh;
  __shared__ int keptGi[PAD];  // separate object: no alias with slab gloads
  int tid = threadIdx.x;

  if (blockIdx.x > 0) {
    // ================= mask worker =================
    int idx = (int)blockIdx.x - 1;
    int cb = idx & 127, rg = idx >> 7;
    if (4 * rg > cb) return;  // strictly lower-tri block
    int rbase = rg * 256;
    sh.m.cbox[tid] = sboxes[rbase + tid];
    sh.m.carea[tid] = sarea[rbase + tid];
    int lane = tid & 63, wid = tid >> 6;
    float4 bj = sboxes[cb * 64 + lane];
    float aB = sarea[cb * 64 + lane];
    __syncthreads();
    int rlim = cb * 64 + 64;
#pragma unroll 8
    for (int i = 0; i < 64; ++i) {
      int r = rbase + (wid << 6) + i;
      if (r >= rlim) break;  // strictly-lower words: skip (stay poison)
      float4 bi = sh.m.cbox[(wid << 6) + i];
      float aA = sh.m.carea[(wid << 6) + i];
      float lxv = fmaxf(bi.x, bj.x), lyv = fmaxf(bi.y, bj.y);
      float rxv = fminf(bi.z, bj.z), ryv = fminf(bi.w, bj.w);
      float iw = fmaxf(rxv - lxv, 0.0f), ih = fmaxf(ryv - lyv, 0.0f);
      float inter = iw * ih;
      float u = aA + aB - inter + 1e-8f;  // exact ref assoc order
      float sA = inter * 33554432.0f;     // * 2^25, exact
      float sB = u * 16777216.0f;         // * 2^24, exact
      u64 bits = __ballot(((sA - sB) - u) > 0.0f);
      if ((r >> 6) == cb) bits &= ~((2ull << (r & 63)) - 1ull);  // j > r only
      if (lane == 0)
        __hip_atomic_store(&mask[(size_t)r * 128 + cb], bits,
                           __ATOMIC_RELAXED, __HIP_MEMORY_SCOPE_AGENT);
    }
    __syncthreads();  // all waves' stores drained (barrier semantics)
    if (tid == 0)
      __hip_atomic_fetch_add(&ctr[cb >> 3], 1, __ATOMIC_RELEASE,
                             __HIP_MEMORY_SCOPE_AGENT);
    return;
  }

  // ================= scan block (wave 0 only) =================
  if (tid >= 64) return;
  int lane = tid;
  int cnt = 0;
  const char* mb = (const char*)mask;

  for (int p = 0; p < NPANEL; ++p) {
    int base = p * PANW;
    // gate: col-panel p fully computed
    int need = 16 * p + 12;
    while (__hip_atomic_load(&ctr[p], __ATOMIC_RELAXED,
                             __HIP_MEMORY_SCOPE_AGENT) < need)
      __builtin_amdgcn_s_sleep(8);
    (void)__hip_atomic_load(&ctr[p], __ATOMIC_ACQUIRE,
                            __HIP_MEMORY_SCOPE_AGENT);  // invalidate caches

    // half-1 slab copy (rows base..base+256) + entry gather — one vmcnt window
    {
      const char* srcB = mb + (size_t)base * 1024 + (size_t)p * 64;
#pragma unroll
      for (int it = 0; it < 16; ++it) {
        const char* g = srcB + (size_t)(it * 16 + (lane >> 2)) * 1024 + (lane & 3) * 16;
        gload_lds16(g, &sh.slab[0] + it * 128);
      }
    }
    u64 acc = 0ull;
    for (int k = (lane >> 3); k < cnt; k += 8)
      acc |= mask[(size_t)keptGi[k] * 128 + p * 8 + (lane & 7)];

    asm volatile("s_waitcnt vmcnt(0)" ::: "memory");
    __builtin_amdgcn_sched_barrier(0);

    // half-2 copy (rows base+256..base+512): outstanding during words 0..3
    {
      const char* srcB = mb + (size_t)(base + 256) * 1024 + (size_t)p * 64;
#pragma unroll
      for (int it = 0; it < 16; ++it) {
        const char* g = srcB + (size_t)(it * 16 + (lane >> 2)) * 1024 + (lane & 3) * 16;
        gload_lds16(g, &sh.slab[0] + (16 + it) * 128);
      }
    }

    acc |= __shfl_xor(acc, 8);
    acc |= __shfl_xor(acc, 16);
    acc |= __shfl_xor(acc, 32);
    u64 remv = acc;             // lane holds panel word (lane&7)
    u64 cur = __shfl(remv, 0);
    const u64* sl = sh.slab;
    int w = 0;

    while (cnt < PAD) {
      u64 inv = ~cur;
      if (inv == 0ull) {  // word exhausted
        if (++w == 8) break;
        if (w == 4) {  // entering rows >= 256: half-2 must be resident
          asm volatile("s_waitcnt vmcnt(0)" ::: "memory");
          __builtin_amdgcn_sched_barrier(0);
        }
        cur = __shfl(remv, w);
        continue;
      }
      // up to 4 candidate bits (R13 proven body)
      int b1 = __ffsll(inv) - 1;
      u64 i2 = inv & (inv - 1);
      int b2 = i2 ? (__ffsll(i2) - 1) : -1;
      u64 i3 = i2 ? (i2 & (i2 - 1)) : 0ull;
      int b3 = i3 ? (__ffsll(i3) - 1) : -1;
      u64 i4 = i3 ? (i3 & (i3 - 1)) : 0ull;
      int b4 = i4 ? (__ffsll(i4) - 1) : -1;
      int li1 = (w << 6) + b1;
      int li2 = (b2 >= 0) ? ((w << 6) + b2) : li1;
      int li3 = (b3 >= 0) ? ((w << 6) + b3) : li1;
      int li4 = (b4 >= 0) ? ((w << 6) + b4) : li1;
      u64 mA1 = sl[li1 * 8 + w], sA1 = sl[li1 * 8 + (lane & 7)];
      u64 mA2 = sl[li2 * 8 + w], sA2 = sl[li2 * 8 + (lane & 7)];
      u64 mA3 = sl[li3 * 8 + w], sA3 = sl[li3 * 8 + (lane & 7)];
      u64 mA4 = sl[li4 * 8 + w], sA4 = sl[li4 * 8 + (lane & 7)];
      bool k2 = (b2 >= 0) && !((mA1 >> b2) & 1ull);
      bool k3 = (b3 >= 0) && !((mA1 >> b3) & 1ull) && !(k2 && ((mA2 >> b3) & 1ull));
      bool k4 = (b4 >= 0) && !((mA1 >> b4) & 1ull) && !(k2 && ((mA2 >> b4) & 1ull)) &&
                !(k3 && ((mA3 >> b4) & 1ull));
      if (lane == 0) kept[cnt] = base + li1;
      keptGi[cnt] = base + li1;
      cnt++;
      cur |= mA1 | (1ull << b1);
      remv |= sA1;
      if (cnt >= PAD) break;
      if (k2) {
        if (lane == 0) kept[cnt] = base + li2;
        keptGi[cnt] = base + li2;
        cnt++;
        cur |= mA2 | (1ull << b2);
        remv |= sA2;
        if (cnt >= PAD) break;
      }
      if (k3) {
        if (lane == 0) kept[cnt] = base + li3;
        keptGi[cnt] = base + li3;
        cnt++;
        cur |= mA3 | (1ull << b3);
        remv |= sA3;
        if (cnt >= PAD) break;
      }
      if (k4) {
        if (lane == 0) kept[cnt] = base + li4;
        keptGi[cnt] = base + li4;
        cnt++;
        cur |= mA4 | (1ull << b4);
        remv |= sA4;
        if (cnt >= PAD) break;
      }
    }
    if (cnt >= PAD) break;
  }
  asm volatile("s_waitcnt vmcnt(0)" ::: "memory");  // drain any outstanding copy
  if (lane == 0) *num_kept = cnt;
}

// ---------------- K5: gather outputs ----------------
__global__ __launch_bounds__(128) void gather_kernel(
    const int* __restrict__ kept, const int* __restrict__ num_kept_p,
    const int* __restrict__ sortedIdx, const float4* __restrict__ sortedBoxes,
    const float* __restrict__ scores, float* __restrict__ out) {
  int r = blockIdx.x;  // 0..299
  int t = threadIdx.x;
  float* boxes_out = out;             // (300,4)
  float* scores_out = out + PAD * 4;  // (300,81)
  int nk = *num_kept_p;
  bool valid = r < nk;
  int pos = valid ? kept[r] : 0;
  if (t < NCLS) {
    int orig = sortedIdx[pos];
    scores_out[(size_t)r * NCLS + t] = valid ? scores[(size_t)orig * NCLS + t] : 0.0f;
  }
  if (t == 96) {
    float4 b = sortedBoxes[pos];
    if (!valid) b = make_float4(0.f, 0.f, 0.f, 0.f);
    ((float4*)boxes_out)[r] = b;
  }
}

extern "C" void kernel_launch(void* const* d_in, const int* in_sizes, int n_in,
                              void* d_out, int out_size, void* d_ws, size_t ws_size,
                              hipStream_t stream) {
  const float* meta = (const float*)d_in[0];
  const float* deltas = (const float*)d_in[1];
  const float* proposals = (const float*)d_in[2];
  const float* scores = (const float*)d_in[3];
  float* out = (float*)d_out;
  char* ws = (char*)d_ws;

  float4* sel = (float4*)(ws + 0);               // 131072 B
  u64* keys = (u64*)(ws + 131072);               // 65536 B
  int* rank = (int*)(ws + 196608);               // 32768 B
  int* sortedIdx = (int*)(ws + 229376);          // 32768 B
  float4* sortedBoxes = (float4*)(ws + 262144);  // 131072 B
  float* sortedArea = (float*)(ws + 393216);     // 32768 B
  int* kept = (int*)(ws + 425984);               // 1200 B
  int* num_kept = (int*)(ws + 428032);           // 4 B
  int* ctr = (int*)(ws + 428096);                // 64 B
  u64* mask = (u64*)(ws + 458752);               // 8 MiB row-major

  decode_kernel<<<N / 32, 256, 0, stream>>>(meta, deltas, proposals, scores, sel, keys, rank, ctr);
  rank_kernel<<<dim3(N / 256, N / 256), 256, 0, stream>>>(keys, rank);
  scatter_kernel<<<N / 256, 256, 0, stream>>>(rank, sel, sortedIdx, sortedBoxes, sortedArea);
  mask_scan_kernel<<<1 + 128 * 32, 256, 0, stream>>>(sortedBoxes, sortedArea, mask, kept, num_kept, ctr);
  gather_kernel<<<PAD, 128, 0, stream>>>(kept, num_kept, sortedIdx, sortedBoxes, scores, out);
}

// Round 16
// 84.073 us; speedup vs baseline: 1.4767x; 1.2328x over previous
//
#include <hip/hip_runtime.h>

#define N 8192
#define NCLS 81
#define PAD 300
#define NPANEL 16
#define PANW 512

typedef unsigned long long u64;

__device__ __forceinline__ void gload_lds16(const void* g, void* l) {
  __builtin_amdgcn_global_load_lds(
      (const __attribute__((address_space(1))) unsigned int*)g,
      (__attribute__((address_space(3))) unsigned int*)l, 16, 0, 0);
}

// ---------------- K1: decode, 8 lanes per row + ctr/rank zero ----------------
__global__ __launch_bounds__(256) void decode_kernel(
    const float* __restrict__ meta, const float* __restrict__ deltas,
    const float* __restrict__ proposals, const float* __restrict__ scores,
    float4* __restrict__ sel, u64* __restrict__ keys, int* __restrict__ rank,
    int* __restrict__ ctr) {
  int tid = threadIdx.x;
  if (blockIdx.x == 0 && tid < 16) ctr[tid] = 0;  // col-panel counters
  int row = blockIdx.x * 32 + (tid >> 3);
  int sub = tid & 7;
  const float* srow = scores + (size_t)row * NCLS;
  float bs = -1e30f, ms = -1e30f;
  int best = 0;
  for (int c = sub; c < NCLS; c += 8) {
    float v = srow[c];
    if (v > bs) { bs = v; best = c; }
    if (c > 0) ms = fmaxf(ms, v);
  }
#pragma unroll
  for (int d = 1; d < 8; d <<= 1) {
    float ob = __shfl_xor(bs, d);
    int oi = __shfl_xor(best, d);
    float om = __shfl_xor(ms, d);
    if (ob > bs || (ob == bs && oi < best)) { bs = ob; best = oi; }
    ms = fmaxf(ms, om);
  }
  if (sub == 0) {
    float W = meta[1], sc = meta[2], H = meta[0];
    const float* p = proposals + row * 4;
    float x1 = p[0] / sc, y1 = p[1] / sc, x2 = p[2] / sc, y2 = p[3] / sc;
    float w = x2 - x1 + 1.0f, h = y2 - y1 + 1.0f;
    float cx = x1 + 0.5f * w, cy = y1 + 0.5f * h;
    float4 d4 = *(const float4*)(deltas + (size_t)row * (4 * NCLS) + best * 4);
    float pcx = d4.x * w + cx, pcy = d4.y * h + cy;
    float pw = expf(d4.z) * w, ph = expf(d4.w) * h;
    float lx = W - 1.0f, ly = H - 1.0f;
    float ox1 = fminf(fmaxf(pcx - 0.5f * pw, 0.0f), lx);
    float oy1 = fminf(fmaxf(pcy - 0.5f * ph, 0.0f), ly);
    float ox2 = fminf(fmaxf(pcx + 0.5f * pw, 0.0f), lx);
    float oy2 = fminf(fmaxf(pcy + 0.5f * ph, 0.0f), ly);
    sel[row] = make_float4(ox1, oy1, ox2, oy2);
    keys[row] = ((u64)(~__float_as_uint(ms)) << 32) | (unsigned)row;
    rank[row] = 0;
  }
}

// ---------------- K2a: brute-force rank, LDS-tiled ----------------
__global__ __launch_bounds__(256) void rank_kernel(
    const u64* __restrict__ keys, int* __restrict__ rank) {
  __shared__ u64 kt[256];
  int tid = threadIdx.x;
  int i = blockIdx.x * 256 + tid;
  kt[tid] = keys[blockIdx.y * 256 + tid];
  u64 ki = keys[i];
  __syncthreads();
  int c = 0;
#pragma unroll 8
  for (int t = 0; t < 256; ++t) c += (kt[t] < ki);
  atomicAdd(&rank[i], c);
}

// ---------------- K2b: scatter into sorted order (+ exact area) ----------------
__global__ __launch_bounds__(256) void scatter_kernel(
    const int* __restrict__ rank, const float4* __restrict__ sel,
    int* __restrict__ sortedIdx, float4* __restrict__ sortedBoxes,
    float* __restrict__ sortedArea) {
  int i = blockIdx.x * 256 + threadIdx.x;
  int r = rank[i];
  float4 b = sel[i];
  sortedIdx[r] = i;
  sortedBoxes[r] = b;
  sortedArea[r] = fmaxf(b.z - b.x, 0.0f) * fmaxf(b.w - b.y, 0.0f);
}

// ---------------- K3+K4 fused: mask workers + gated greedy scan ----------------
// R14 structure with two fixes: (1) cb-MAJOR worker dispatch (cb = idx>>5) so
// col-panel p completes at ~(p/16) of mask time — the scan trails the mask
// wavefront instead of waiting for the whole mask before its last panels;
// (2) worker unroll-2 (two rows/iteration, independent chains) to double MLP
// against the ~120cy LDS broadcast latency at 12 waves/CU (VGPR-capped).
// Coherence scheme unchanged (proven R14): agent-scope atomic word stores +
// release atomicAdd on ctr[cp]; scan polls relaxed + acquire per gate (16
// total, OFF the keep chain). Deadlock-free: workers never wait; ctr monotone;
// correctness independent of dispatch order. expected[cp] = 16*cp + 12.
__global__ __launch_bounds__(256) void mask_scan_kernel(
    const float4* __restrict__ sboxes, const float* __restrict__ sarea,
    u64* __restrict__ mask, int* __restrict__ kept, int* __restrict__ num_kept,
    int* __restrict__ ctr) {
  __shared__ union {
    u64 slab[PANW * 8];                                // 32 KiB (scan)
    struct { float4 cbox[256]; float carea[256]; } m;  // 5 KiB (mask)
  } sh;
  __shared__ int keptGi[PAD];  // separate object: no alias with slab gloads
  int tid = threadIdx.x;

  if (blockIdx.x > 0) {
    // ================= mask worker =================
    int idx = (int)blockIdx.x - 1;
    int cb = idx >> 5, rg = idx & 31;  // cb-major: panel p done early
    if (4 * rg > cb) return;           // strictly lower-tri block
    int rbase = rg * 256;
    sh.m.cbox[tid] = sboxes[rbase + tid];
    sh.m.carea[tid] = sarea[rbase + tid];
    int lane = tid & 63, wid = tid >> 6;
    float4 bj = sboxes[cb * 64 + lane];
    float aB = sarea[cb * 64 + lane];
    __syncthreads();
    int rlim = cb * 64 + 64;
    int r0 = rbase + (wid << 6);
#pragma unroll 4
    for (int i = 0; i < 32; ++i) {
      int r1 = r0 + i, r2 = r0 + i + 32;
      if (r1 >= rlim) break;  // r2 rows also >= rlim later; all remaining lower-tri
      float4 bi1 = sh.m.cbox[(wid << 6) + i];
      float aA1 = sh.m.carea[(wid << 6) + i];
      float4 bi2 = sh.m.cbox[(wid << 6) + i + 32];
      float aA2 = sh.m.carea[(wid << 6) + i + 32];
      // row 1
      float lx1 = fmaxf(bi1.x, bj.x), ly1 = fmaxf(bi1.y, bj.y);
      float rx1 = fminf(bi1.z, bj.z), ry1 = fminf(bi1.w, bj.w);
      float in1 = fmaxf(rx1 - lx1, 0.0f) * fmaxf(ry1 - ly1, 0.0f);
      float u1 = aA1 + aB - in1 + 1e-8f;
      u64 bits1 = __ballot(((in1 * 33554432.0f - u1 * 16777216.0f) - u1) > 0.0f);
      // row 2 (independent chain)
      float lx2 = fmaxf(bi2.x, bj.x), ly2 = fmaxf(bi2.y, bj.y);
      float rx2 = fminf(bi2.z, bj.z), ry2 = fminf(bi2.w, bj.w);
      float in2 = fmaxf(rx2 - lx2, 0.0f) * fmaxf(ry2 - ly2, 0.0f);
      float u2 = aA2 + aB - in2 + 1e-8f;
      u64 bits2 = __ballot(((in2 * 33554432.0f - u2 * 16777216.0f) - u2) > 0.0f);
      if ((r1 >> 6) == cb) bits1 &= ~((2ull << (r1 & 63)) - 1ull);  // j > r only
      if ((r2 >> 6) == cb) bits2 &= ~((2ull << (r2 & 63)) - 1ull);
      if (lane == 0) {
        __hip_atomic_store(&mask[(size_t)r1 * 128 + cb], bits1,
                           __ATOMIC_RELAXED, __HIP_MEMORY_SCOPE_AGENT);
        if (r2 < rlim)
          __hip_atomic_store(&mask[(size_t)r2 * 128 + cb], bits2,
                             __ATOMIC_RELAXED, __HIP_MEMORY_SCOPE_AGENT);
      }
    }
    __syncthreads();  // all waves' stores drained (barrier semantics)
    if (tid == 0)
      __hip_atomic_fetch_add(&ctr[cb >> 3], 1, __ATOMIC_RELEASE,
                             __HIP_MEMORY_SCOPE_AGENT);
    return;
  }

  // ================= scan block (wave 0 only) =================
  if (tid >= 64) return;
  int lane = tid;
  int cnt = 0;
  const char* mb = (const char*)mask;

  for (int p = 0; p < NPANEL; ++p) {
    int base = p * PANW;
    // gate: col-panel p fully computed
    int need = 16 * p + 12;
    while (__hip_atomic_load(&ctr[p], __ATOMIC_RELAXED,
                             __HIP_MEMORY_SCOPE_AGENT) < need)
      __builtin_amdgcn_s_sleep(8);
    (void)__hip_atomic_load(&ctr[p], __ATOMIC_ACQUIRE,
                            __HIP_MEMORY_SCOPE_AGENT);  // invalidate caches

    // half-1 slab copy (rows base..base+256) + entry gather — one vmcnt window
    {
      const char* srcB = mb + (size_t)base * 1024 + (size_t)p * 64;
#pragma unroll
      for (int it = 0; it < 16; ++it) {
        const char* g = srcB + (size_t)(it * 16 + (lane >> 2)) * 1024 + (lane & 3) * 16;
        gload_lds16(g, &sh.slab[0] + it * 128);
      }
    }
    u64 acc = 0ull;
    for (int k = (lane >> 3); k < cnt; k += 8)
      acc |= mask[(size_t)keptGi[k] * 128 + p * 8 + (lane & 7)];

    asm volatile("s_waitcnt vmcnt(0)" ::: "memory");
    __builtin_amdgcn_sched_barrier(0);

    // half-2 copy (rows base+256..base+512): outstanding during words 0..3
    {
      const char* srcB = mb + (size_t)(base + 256) * 1024 + (size_t)p * 64;
#pragma unroll
      for (int it = 0; it < 16; ++it) {
        const char* g = srcB + (size_t)(it * 16 + (lane >> 2)) * 1024 + (lane & 3) * 16;
        gload_lds16(g, &sh.slab[0] + (16 + it) * 128);
      }
    }

    acc |= __shfl_xor(acc, 8);
    acc |= __shfl_xor(acc, 16);
    acc |= __shfl_xor(acc, 32);
    u64 remv = acc;             // lane holds panel word (lane&7)
    u64 cur = __shfl(remv, 0);
    const u64* sl = sh.slab;
    int w = 0;

    while (cnt < PAD) {
      u64 inv = ~cur;
      if (inv == 0ull) {  // word exhausted
        if (++w == 8) break;
        if (w == 4) {  // entering rows >= 256: half-2 must be resident
          asm volatile("s_waitcnt vmcnt(0)" ::: "memory");
          __builtin_amdgcn_sched_barrier(0);
        }
        cur = __shfl(remv, w);
        continue;
      }
      // up to 4 candidate bits (R13 proven body)
      int b1 = __ffsll(inv) - 1;
      u64 i2 = inv & (inv - 1);
      int b2 = i2 ? (__ffsll(i2) - 1) : -1;
      u64 i3 = i2 ? (i2 & (i2 - 1)) : 0ull;
      int b3 = i3 ? (__ffsll(i3) - 1) : -1;
      u64 i4 = i3 ? (i3 & (i3 - 1)) : 0ull;
      int b4 = i4 ? (__ffsll(i4) - 1) : -1;
      int li1 = (w << 6) + b1;
      int li2 = (b2 >= 0) ? ((w << 6) + b2) : li1;
      int li3 = (b3 >= 0) ? ((w << 6) + b3) : li1;
      int li4 = (b4 >= 0) ? ((w << 6) + b4) : li1;
      u64 mA1 = sl[li1 * 8 + w], sA1 = sl[li1 * 8 + (lane & 7)];
      u64 mA2 = sl[li2 * 8 + w], sA2 = sl[li2 * 8 + (lane & 7)];
      u64 mA3 = sl[li3 * 8 + w], sA3 = sl[li3 * 8 + (lane & 7)];
      u64 mA4 = sl[li4 * 8 + w], sA4 = sl[li4 * 8 + (lane & 7)];
      bool k2 = (b2 >= 0) && !((mA1 >> b2) & 1ull);
      bool k3 = (b3 >= 0) && !((mA1 >> b3) & 1ull) && !(k2 && ((mA2 >> b3) & 1ull));
      bool k4 = (b4 >= 0) && !((mA1 >> b4) & 1ull) && !(k2 && ((mA2 >> b4) & 1ull)) &&
                !(k3 && ((mA3 >> b4) & 1ull));
      if (lane == 0) kept[cnt] = base + li1;
      keptGi[cnt] = base + li1;
      cnt++;
      cur |= mA1 | (1ull << b1);
      remv |= sA1;
      if (cnt >= PAD) break;
      if (k2) {
        if (lane == 0) kept[cnt] = base + li2;
        keptGi[cnt] = base + li2;
        cnt++;
        cur |= mA2 | (1ull << b2);
        remv |= sA2;
        if (cnt >= PAD) break;
      }
      if (k3) {
        if (lane == 0) kept[cnt] = base + li3;
        keptGi[cnt] = base + li3;
        cnt++;
        cur |= mA3 | (1ull << b3);
        remv |= sA3;
        if (cnt >= PAD) break;
      }
      if (k4) {
        if (lane == 0) kept[cnt] = base + li4;
        keptGi[cnt] = base + li4;
        cnt++;
        cur |= mA4 | (1ull << b4);
        remv |= sA4;
        if (cnt >= PAD) break;
      }
    }
    if (cnt >= PAD) break;
  }
  asm volatile("s_waitcnt vmcnt(0)" ::: "memory");  // drain any outstanding copy
  if (lane == 0) *num_kept = cnt;
}

// ---------------- K5: gather outputs ----------------
__global__ __launch_bounds__(128) void gather_kernel(
    const int* __restrict__ kept, const int* __restrict__ num_kept_p,
    const int* __restrict__ sortedIdx, const float4* __restrict__ sortedBoxes,
    const float* __restrict__ scores, float* __restrict__ out) {
  int r = blockIdx.x;  // 0..299
  int t = threadIdx.x;
  float* boxes_out = out;             // (300,4)
  float* scores_out = out + PAD * 4;  // (300,81)
  int nk = *num_kept_p;
  bool valid = r < nk;
  int pos = valid ? kept[r] : 0;
  if (t < NCLS) {
    int orig = sortedIdx[pos];
    scores_out[(size_t)r * NCLS + t] = valid ? scores[(size_t)orig * NCLS + t] : 0.0f;
  }
  if (t == 96) {
    float4 b = sortedBoxes[pos];
    if (!valid) b = make_float4(0.f, 0.f, 0.f, 0.f);
    ((float4*)boxes_out)[r] = b;
  }
}

extern "C" void kernel_launch(void* const* d_in, const int* in_sizes, int n_in,
                              void* d_out, int out_size, void* d_ws, size_t ws_size,
                              hipStream_t stream) {
  const float* meta = (const float*)d_in[0];
  const float* deltas = (const float*)d_in[1];
  const float* proposals = (const float*)d_in[2];
  const float* scores = (const float*)d_in[3];
  float* out = (float*)d_out;
  char* ws = (char*)d_ws;

  float4* sel = (float4*)(ws + 0);               // 131072 B
  u64* keys = (u64*)(ws + 131072);               // 65536 B
  int* rank = (int*)(ws + 196608);               // 32768 B
  int* sortedIdx = (int*)(ws + 229376);          // 32768 B
  float4* sortedBoxes = (float4*)(ws + 262144);  // 131072 B
  float* sortedArea = (float*)(ws + 393216);     // 32768 B
  int* kept = (int*)(ws + 425984);               // 1200 B
  int* num_kept = (int*)(ws + 428032);           // 4 B
  int* ctr = (int*)(ws + 428096);                // 64 B
  u64* mask = (u64*)(ws + 458752);               // 8 MiB row-major

  decode_kernel<<<N / 32, 256, 0, stream>>>(meta, deltas, proposals, scores, sel, keys, rank, ctr);
  rank_kernel<<<dim3(N / 256, N / 256), 256, 0, stream>>>(keys, rank);
  scatter_kernel<<<N / 256, 256, 0, stream>>>(rank, sel, sortedIdx, sortedBoxes, sortedArea);
  mask_scan_kernel<<<1 + 128 * 32, 256, 0, stream>>>(sortedBoxes, sortedArea, mask, kept, num_kept, ctr);
  gather_kernel<<<PAD, 128, 0, stream>>>(kept, num_kept, sortedIdx, sortedBoxes, scores, out);
}